// Round 9
// baseline (139.425 us; speedup 1.0000x reference)
//
#include <hip/hip_runtime.h>

// CrossProductLayer: out[b, f] = t(b, f) * w[f]
//   f in [0,128)    : x[b,f]^2
//   f in [128,256)  : x[b,f-128]
//   f in [256,8384) : x[b,i]*x[b,j]*0.5, (i,j) = triu_indices(128, k=1)[f-256]
// B=16384, F=8384. 549 MB fp32 output -> HBM-write-bound.
//
// R9: contiguous per-block store streams with REGISTER metadata.
// Each block owns 16 consecutive rows -> one strictly-sequential 536 KB
// write stream (mirrors the 6.7 TB/s fill kernel's structure). The 33
// per-chunk (i,j,ws) descriptors are decoded ONCE per thread into 66 VGPRs
// (fully unrolled, static indexing -> registers, not scratch), so the sweep
// is only: 2 conflict-free LDS reads + 1 dword store per element. Unlike R5
// (4 LDS reads/element -> LDS co-limiting), the LDS pipe here has 2x
// headroom. 1024 blocks x 4 blocks/CU resident = one uniform cohort.
// Sentinel 1.0 at word 128 of each x-row handles singles branch-free.
// fp-exact: *1.0 exact; (xi*xj)*(0.5*w) == ((xi*xj)*0.5)*w (absmax 0.0 R2-R8).

constexpr int BATCH = 16384;
constexpr int NIN   = 128;
constexpr int NFEAT = 2 * NIN + NIN * (NIN - 1) / 2;  // 8384
constexpr int TPB   = 256;
constexpr int ROWS  = 16;                 // consecutive rows per block
constexpr int RS    = 132;                // x-row stride; word 128 = 1.0
constexpr int NCH   = (NFEAT + TPB - 1) / TPB;  // 33 chunks per row

__device__ __forceinline__ int pair_off(int i) { return i * (NIN - 1) - (i * (i - 1)) / 2; }

__global__ __launch_bounds__(TPB, 4) void cpl_kernel(const float* __restrict__ x,
                                                     const float* __restrict__ w,
                                                     float* __restrict__ out) {
    __shared__ float xs[ROWS * RS];  // 8.25 KB
    const int tid = threadIdx.x;
    const int r0  = blockIdx.x * ROWS;

    // Stage 16x128 x-tile (512 float4, 2 per thread). RS*4=528 is 16B-aligned.
#pragma unroll
    for (int p = 0; p < 2; ++p) {
        const int idx = p * TPB + tid;
        const int r = idx >> 5, c4 = (idx & 31) * 4;
        float4 v = *reinterpret_cast<const float4*>(x + (size_t)(r0 + r) * NIN + c4);
        *reinterpret_cast<float4*>(&xs[r * RS + c4]) = v;
    }
    if (tid < ROWS) xs[tid * RS + 128] = 1.0f;  // sentinel for singles

    // Decode this thread's 33 chunk descriptors into registers (once/block).
    unsigned int ij[NCH];  // (i<<8)|j
    float        ws[NCH];
#pragma unroll
    for (int k = 0; k < NCH; ++k) {
        const int f = k * TPB + tid;
        if (f >= NFEAT) { ij[k] = 0; ws[k] = 0.0f; continue; }  // only k=32, tid>=192
        const float wv = w[f];
        if (f < NIN)          { ij[k] = (unsigned)((f << 8) | f);                 ws[k] = wv; }
        else if (f < 2 * NIN) { ij[k] = (unsigned)(((f - NIN) << 8) | 128);       ws[k] = wv; }
        else {
            const int p = f - 2 * NIN;
            float s = sqrtf((float)(65025 - 8 * p));
            int   i = (int)((255.0f - s) * 0.5f);
            i = min(max(i, 0), NIN - 2);
            while (pair_off(i + 1) <= p) ++i;   // exact integer fix-up
            while (pair_off(i)     >  p) --i;
            const int j = i + 1 + (p - pair_off(i));
            ij[k] = (unsigned)((i << 8) | j);
            ws[k] = wv * 0.5f;                  // exact scaling
        }
    }
    __syncthreads();

    // Sweep: 16 rows x 33 chunks, strictly sequential 536 KB per block.
    // Per element: 2 LDS reads (i near-broadcast, j lane-stride-1: both
    // conflict-free) + 1 dword store. No global loads, no further barriers.
    for (int r = 0; r < ROWS; ++r) {
        const float* xr   = &xs[r * RS];
        float*       orow = out + (size_t)(r0 + r) * NFEAT;
#pragma unroll
        for (int k = 0; k < NCH; ++k) {
            const int f = k * TPB + tid;
            if (k < NCH - 1 || f < NFEAT) {     // guard folds away except k=32
                const unsigned int e = ij[k];
                orow[f] = xr[e >> 8] * xr[e & 255] * ws[k];
            }
        }
    }
}

extern "C" void kernel_launch(void* const* d_in, const int* in_sizes, int n_in,
                              void* d_out, int out_size, void* d_ws, size_t ws_size,
                              hipStream_t stream) {
    const float* x = (const float*)d_in[0];  // [16384, 128]
    const float* w = (const float*)d_in[1];  // [8384]
    float*     out = (float*)d_out;          // [16384, 8384]

    cpl_kernel<<<dim3(BATCH / ROWS), dim3(TPB), 0, stream>>>(x, w, out);  // 1024 blocks
}

// Round 10
// 98.879 us; speedup vs baseline: 1.4101x; 1.4101x over previous
//
#include <hip/hip_runtime.h>

// CrossProductLayer: out[b, f] = t(b, f) * w[f]
//   f in [0,128)    : x[b,f]^2
//   f in [128,256)  : x[b,f-128]
//   f in [256,8384) : x[b,i]*x[b,j]*0.5, (i,j) = triu_indices(128, k=1)[f-256]
// B=16384, F=8384. 549 MB fp32 output -> HBM-write-bound.
//
// R10 = R2 (champion, 101.7 us) with ONE change: non-temporal dword stores.
// Theory: the 549 MB streaming store front continuously evicts the shared
// x-tiles from each XCD's 4 MB L2 (33 blocks re-read each tile), forcing
// L3 re-fetches on the same path as the write drain. nt-stores keep L2
// clean so x stays L2-resident. Wave stores are 256 B contiguous (full
// lines) -> no partial-line risk. R7 tested nt only bundled with a
// work-remap (which R9 showed scatters the instantaneous write front);
// this deconfounds it.
// fp-exact: same op order as R2 (absmax 0.0 in R2-R9).

constexpr int BATCH = 16384;
constexpr int NIN   = 128;
constexpr int NFEAT = 2 * NIN + NIN * (NIN - 1) / 2;  // 8384
constexpr int TPB   = 256;
constexpr int BROWS = 32;

__device__ __forceinline__ int pair_off(int i) { return i * (NIN - 1) - (i * (i - 1)) / 2; }

__global__ __launch_bounds__(TPB) void cpl_kernel(const float* __restrict__ x,
                                                  const float* __restrict__ w,
                                                  float* __restrict__ out) {
    __shared__ float xs[BROWS * NIN];

    const int tid = threadIdx.x;
    const int b0  = blockIdx.y * BROWS;

    // Cooperative tile load: 32 rows x 128 floats = 1024 float4, 4 per thread.
    {
        const float4* src = reinterpret_cast<const float4*>(x + (size_t)b0 * NIN);
        float4*       dst = reinterpret_cast<float4*>(xs);
#pragma unroll
        for (int k = 0; k < (BROWS * NIN / 4) / TPB; ++k)
            dst[k * TPB + tid] = src[k * TPB + tid];
    }
    __syncthreads();

    const int f = blockIdx.x * TPB + tid;
    if (f >= NFEAT) return;

    // Decode this thread's feature once; amortized over BROWS rows.
    // Branches wave-uniform: boundaries 128/256 are multiples of 64.
    int i1, i2, mode;  // 0=square, 1=single, 2=pair
    if (f < NIN) {
        i1 = f; i2 = f; mode = 0;
    } else if (f < 2 * NIN) {
        i1 = f - NIN; i2 = f - NIN; mode = 1;
    } else {
        const int p = f - 2 * NIN;
        float s = sqrtf((float)(65025 - 8 * p));  // invert off(i) <= p
        int   i = (int)((255.0f - s) * 0.5f);
        i = min(max(i, 0), NIN - 2);
        while (pair_off(i + 1) <= p) ++i;  // exact integer fix-up
        while (pair_off(i)     >  p) --i;
        i1 = i;
        i2 = i + 1 + (p - pair_off(i));
        mode = 2;
    }
    const float wf = w[f];

    float* op = out + (size_t)b0 * NFEAT + f;
#pragma unroll
    for (int b = 0; b < BROWS; ++b) {
        const float xi = xs[b * NIN + i1];
        const float xj = xs[b * NIN + i2];  // lane-stride-1: conflict-free
        float p = xi * xj;                  // squares & pairs
        if (mode == 1) p = xi;              // singles
        if (mode == 2) p *= 0.5f;           // pairs (same fp order as ref)
        __builtin_nontemporal_store(p * wf, op + (size_t)b * NFEAT);
    }
}

extern "C" void kernel_launch(void* const* d_in, const int* in_sizes, int n_in,
                              void* d_out, int out_size, void* d_ws, size_t ws_size,
                              hipStream_t stream) {
    const float* x = (const float*)d_in[0];  // [16384, 128]
    const float* w = (const float*)d_in[1];  // [8384]
    float*     out = (float*)d_out;          // [16384, 8384]

    dim3 grid((NFEAT + TPB - 1) / TPB,  // 33 feature windows
              BATCH / BROWS);           // 512 row groups
    cpl_kernel<<<grid, TPB, 0, stream>>>(x, w, out);
}

// Round 11
// 96.677 us; speedup vs baseline: 1.4422x; 1.0228x over previous
//
#include <hip/hip_runtime.h>

// CrossProductLayer: out[b, f] = t(b, f) * w[f]
//   f in [0,128)    : x[b,f]^2
//   f in [128,256)  : x[b,f-128]
//   f in [256,8384) : x[b,i]*x[b,j]*0.5, (i,j) = triu_indices(128, k=1)[f-256]
// B=16384, F=8384. 549 MB fp32 output -> HBM-write-bound.
//
// R11 = R10 (champion, 98.9 us: R2 structure + nt dword stores) with the
// per-block setup front shrunk:
//  1. BROWS 32 -> 64: halves block count (8448), halves barrier/setup
//     events, amortizes the pair decode 2x. 32 KB LDS -> still 5 blocks/CU.
//  2. Decode + w[f] load hoisted ABOVE the tile staging so their latency
//     overlaps the staging loads instead of serializing after the barrier.
// fp-exact: same op order as R2/R10 (absmax 0.0 in R2-R10).

constexpr int BATCH = 16384;
constexpr int NIN   = 128;
constexpr int NFEAT = 2 * NIN + NIN * (NIN - 1) / 2;  // 8384
constexpr int TPB   = 256;
constexpr int BROWS = 64;

__device__ __forceinline__ int pair_off(int i) { return i * (NIN - 1) - (i * (i - 1)) / 2; }

__global__ __launch_bounds__(TPB) void cpl_kernel(const float* __restrict__ x,
                                                  const float* __restrict__ w,
                                                  float* __restrict__ out) {
    __shared__ float xs[BROWS * NIN];  // 32 KB

    const int tid = threadIdx.x;
    const int b0  = blockIdx.y * BROWS;
    const int f   = blockIdx.x * TPB + tid;
    const int fc  = min(f, NFEAT - 1);  // clamp for safe early decode/load

    // Issue w-load + decode FIRST: latency overlaps the staging loads below.
    const float wf = w[fc];
    int i1, i2, mode;  // 0=square, 1=single, 2=pair
    if (fc < NIN) {
        i1 = fc; i2 = fc; mode = 0;
    } else if (fc < 2 * NIN) {
        i1 = fc - NIN; i2 = fc - NIN; mode = 1;
    } else {
        const int p = fc - 2 * NIN;
        float s = sqrtf((float)(65025 - 8 * p));  // invert off(i) <= p
        int   i = (int)((255.0f - s) * 0.5f);
        i = min(max(i, 0), NIN - 2);
        while (pair_off(i + 1) <= p) ++i;  // exact integer fix-up
        while (pair_off(i)     >  p) --i;
        i1 = i;
        i2 = i + 1 + (p - pair_off(i));
        mode = 2;
    }

    // Cooperative tile load: 64 rows x 128 floats = 2048 float4, 8 per thread.
    {
        const float4* src = reinterpret_cast<const float4*>(x + (size_t)b0 * NIN);
        float4*       dst = reinterpret_cast<float4*>(xs);
#pragma unroll
        for (int k = 0; k < (BROWS * NIN / 4) / TPB; ++k)
            dst[k * TPB + tid] = src[k * TPB + tid];
    }
    __syncthreads();

    if (f >= NFEAT) return;

    float* op = out + (size_t)b0 * NFEAT + f;
#pragma unroll
    for (int b = 0; b < BROWS; ++b) {
        const float xi = xs[b * NIN + i1];
        const float xj = xs[b * NIN + i2];  // lane-stride-1: conflict-free
        float p = xi * xj;                  // squares & pairs
        if (mode == 1) p = xi;              // singles
        if (mode == 2) p *= 0.5f;           // pairs (same fp order as ref)
        __builtin_nontemporal_store(p * wf, op + (size_t)b * NFEAT);
    }
}

extern "C" void kernel_launch(void* const* d_in, const int* in_sizes, int n_in,
                              void* d_out, int out_size, void* d_ws, size_t ws_size,
                              hipStream_t stream) {
    const float* x = (const float*)d_in[0];  // [16384, 128]
    const float* w = (const float*)d_in[1];  // [8384]
    float*     out = (float*)d_out;          // [16384, 8384]

    dim3 grid((NFEAT + TPB - 1) / TPB,  // 33 feature windows
              BATCH / BROWS);           // 256 row groups
    cpl_kernel<<<grid, TPB, 0, stream>>>(x, w, out);
}